// Round 8
// baseline (872.725 us; speedup 1.0000x reference)
//
#include <hip/hip_runtime.h>
#include <hip/hip_bf16.h>

#define NBH     32          // B*H
#define SEQ     2048
#define DIM     64
#define QBLK    64
#define KBLK    128
#define NCHUNK  (SEQ / KBLK)     // 16
#define PSTR    136              // P row stride in ushorts (272B, 16B-aligned)

typedef __attribute__((ext_vector_type(4))) float f32x4;
typedef __attribute__((ext_vector_type(8))) short bf16x8;

__device__ __forceinline__ unsigned short bfbits(float f) {
    return __builtin_bit_cast(unsigned short, __float2bfloat16(f));
}

// ---------------------------------------------------------------------------
// V prep (unchanged from round 6)
// ---------------------------------------------------------------------------
__global__ __launch_bounds__(256)
void vprep_kernel(const float* __restrict__ v, unsigned short* __restrict__ wsv)
{
    const int blk = blockIdx.x;            // bh*32 + tau
    const int bh  = blk >> 5, tau = blk & 31;
    const float* vp = v + ((size_t)bh * SEQ + tau * 64) * DIM;
    unsigned short* op = wsv + (size_t)blk * 4096;

    for (int fl = threadIdx.x; fl < 512; fl += 256) {
        const int ks1 = fl >> 8, dt = (fl >> 6) & 3, lane = fl & 63;
        const int g = lane >> 4, c = lane & 15;
        const float* sp = vp + (ks1 * 32 + g * 8) * DIM + dt * 16 + c;
        bf16x8 frag;
#pragma unroll
        for (int j = 0; j < 8; ++j)
            frag[j] = (short)bfbits(sp[j * DIM]);
        *reinterpret_cast<bf16x8*>(op + fl * 8) = frag;
    }
}

// ---------------------------------------------------------------------------
// Main kernel (byte-identical to round 6, the 137.8us best)
// ---------------------------------------------------------------------------
__global__ __launch_bounds__(256, 2)
void softmaxv_kernel(const float* __restrict__ scores,
                     const unsigned short* __restrict__ vfrags,
                     float* __restrict__ out)
{
    __shared__ unsigned short p_lds[4][2][16 * PSTR];
    __shared__ float l_lds[4][16];

    const int tid  = threadIdx.x;
    const int w    = tid >> 6;
    const int lane = tid & 63;
    const int g    = lane >> 4;
    const int c    = lane & 15;
    const int h    = lane >> 5;
    const int c2   = lane & 31;

    const int bid = blockIdx.x;
    const int nb  = (bid & 7) * (NBH * 32 / 8) + (bid >> 3);
    const int bh  = nb >> 5;
    const int qb  = nb & 31;
    const int q0  = qb * QBLK;

    const float* sp = scores + ((size_t)bh * SEQ + q0 + w * 16 + h) * SEQ + c2 * 4;
    const unsigned short* vb = vfrags + (size_t)bh * 32 * 4096 + lane * 8;

    unsigned short* pb0 = &p_lds[w][0][0];
    unsigned short* pb1 = &p_lds[w][1][0];

    float lsum[8] = {0.f, 0.f, 0.f, 0.f, 0.f, 0.f, 0.f, 0.f};
    f32x4 acc[4];
#pragma unroll
    for (int dt = 0; dt < 4; ++dt) acc[dt] = (f32x4)0.0f;

#define SLOADS(dst, t)                                                         \
    {                                                                          \
        _Pragma("unroll")                                                      \
        for (int j = 0; j < 8; ++j)                                            \
            dst[j] = *reinterpret_cast<const f32x4*>(                          \
                sp + (size_t)(2 * j) * SEQ + (t) * KBLK);                      \
    }

#define VLOAD(vf, t)                                                           \
    {                                                                          \
        _Pragma("unroll")                                                      \
        for (int ks = 0; ks < 4; ++ks)                                         \
            _Pragma("unroll")                                                  \
            for (int dt = 0; dt < 4; ++dt)                                     \
                vf[ks][dt] = *reinterpret_cast<const bf16x8*>(                 \
                    vb + (size_t)(2 * (t) + (ks >> 1)) * 4096 +                \
                    ((ks & 1) * 4 + dt) * 512);                                \
    }

#define PROC(sreg, pbuf)                                                       \
    {                                                                          \
        _Pragma("unroll")                                                      \
        for (int j = 0; j < 8; ++j) {                                          \
            f32x4 s4 = sreg[j];                                                \
            float p0 = __expf(s4[0]);                                          \
            float p1 = __expf(s4[1]);                                          \
            float p2 = __expf(s4[2]);                                          \
            float p3 = __expf(s4[3]);                                          \
            lsum[j] += (p0 + p1) + (p2 + p3);                                  \
            unsigned lo = (unsigned)bfbits(p0) | ((unsigned)bfbits(p1) << 16); \
            unsigned hi = (unsigned)bfbits(p2) | ((unsigned)bfbits(p3) << 16); \
            *reinterpret_cast<uint2*>(&pbuf[(2 * j + h) * PSTR + c2 * 4]) =    \
                make_uint2(lo, hi);                                            \
        }                                                                      \
        _Pragma("unroll")                                                      \
        for (int ks = 0; ks < 4; ++ks) {                                       \
            const bf16x8 a = *reinterpret_cast<const bf16x8*>(                 \
                &pbuf[c * PSTR + ks * 32 + g * 8]);                            \
            _Pragma("unroll")                                                  \
            for (int dt = 0; dt < 4; ++dt)                                     \
                acc[dt] = __builtin_amdgcn_mfma_f32_16x16x32_bf16(             \
                    a, vf[ks][dt], acc[dt], 0, 0, 0);                          \
        }                                                                      \
    }

    f32x4 sA[8], sB[8];
    bf16x8 vf[4][4];
    SLOADS(sA, 0)
    for (int t = 0; t < NCHUNK; t += 2) {
        VLOAD(vf, t)
        SLOADS(sB, t + 1)
        PROC(sA, pb0)
        VLOAD(vf, t + 1)
        if (t + 2 < NCHUNK) SLOADS(sA, t + 2)
        PROC(sB, pb1)
    }
#undef SLOADS
#undef VLOAD
#undef PROC

#pragma unroll
    for (int j = 0; j < 8; ++j) {
        float l = lsum[j];
        l += __shfl_xor(l, 1);
        l += __shfl_xor(l, 2);
        l += __shfl_xor(l, 4);
        l += __shfl_xor(l, 8);
        l += __shfl_xor(l, 16);
        if (c2 == j) l_lds[w][2 * j + h] = l;
    }

    float* op = out + ((size_t)bh * SEQ + q0 + w * 16) * DIM;
    float rl[4];
#pragma unroll
    for (int r = 0; r < 4; ++r)
        rl[r] = 1.0f / l_lds[w][g * 4 + r];
#pragma unroll
    for (int dt = 0; dt < 4; ++dt)
#pragma unroll
        for (int r = 0; r < 4; ++r)
            op[(g * 4 + r) * DIM + dt * 16 + c] = acc[dt][r] * rl[r];
}

// ---------------------------------------------------------------------------
// PROBE A: pure-read, EXACT round-6 S pattern (64 row-streams per block,
// 512B per row-visit), 4 full sweeps = 2.15 GB. Lands in rocprof top-5.
// ---------------------------------------------------------------------------
__global__ __launch_bounds__(256, 2)
void probe_pattern_kernel(const float* __restrict__ scores, float* __restrict__ sink)
{
    const int tid  = threadIdx.x;
    const int w    = tid >> 6;
    const int lane = tid & 63;
    const int h    = lane >> 5;
    const int c2   = lane & 31;

    const int bid = blockIdx.x;
    const int nb  = (bid & 7) * 128 + (bid >> 3);
    const int bh  = nb >> 5;
    const int qb  = nb & 31;

    const float* sp = scores + ((size_t)bh * SEQ + qb * QBLK + w * 16 + h) * SEQ + c2 * 4;

    f32x4 acc = (f32x4)0.0f;
    for (int rep = 0; rep < 4; ++rep) {
        for (int t = 0; t < NCHUNK; ++t) {
#pragma unroll
            for (int j = 0; j < 8; ++j) {
                f32x4 v = *reinterpret_cast<const f32x4*>(
                    sp + (size_t)(2 * j) * SEQ + t * KBLK);
                acc += v;
            }
        }
    }
    sink[(size_t)bid * 256 + tid] = acc[0] + acc[1] + acc[2] + acc[3];
}

// ---------------------------------------------------------------------------
// PROBE B: pure-read, fully CONTIGUOUS 512KB slab per block, 4 sweeps
// = 2.15 GB. Lands in rocprof top-5.
// ---------------------------------------------------------------------------
__global__ __launch_bounds__(256, 2)
void probe_contig_kernel(const float* __restrict__ scores, float* __restrict__ sink)
{
    const int tid = threadIdx.x;
    const float* sp = scores + (size_t)blockIdx.x * 131072;   // 512KB slab

    f32x4 acc = (f32x4)0.0f;
    for (int rep = 0; rep < 4; ++rep) {
#pragma unroll 8
        for (int it = 0; it < 128; ++it) {
            f32x4 v = *reinterpret_cast<const f32x4*>(sp + (size_t)it * 1024 + tid * 4);
            acc += v;
        }
    }
    sink[(size_t)blockIdx.x * 256 + tid] = acc[0] + acc[1] + acc[2] + acc[3];
}

extern "C" void kernel_launch(void* const* d_in, const int* in_sizes, int n_in,
                              void* d_out, int out_size, void* d_ws, size_t ws_size,
                              hipStream_t stream)
{
    const float* scores = (const float*)d_in[0];
    const float* v      = (const float*)d_in[1];
    float* out          = (float*)d_out;
    unsigned short* wsv = (unsigned short*)d_ws;                       // 8 MB
    float* sink         = (float*)((char*)d_ws + (64u << 20));        // probe sink @64MB

    vprep_kernel<<<dim3(NBH * 32), dim3(256), 0, stream>>>(v, wsv);
    softmaxv_kernel<<<dim3(NBH * (SEQ / QBLK)), dim3(256), 0, stream>>>(scores, wsv, out);
    // --- sacrificial measurement probes (do not touch d_out) ---
    probe_pattern_kernel<<<dim3(1024), dim3(256), 0, stream>>>(scores, sink);
    probe_contig_kernel<<<dim3(1024), dim3(256), 0, stream>>>(scores, sink + (1024 * 256));
}